// Round 1
// 289.500 us; speedup vs baseline: 1.0792x; 1.0792x over previous
//
#include <hip/hip_runtime.h>
#include <cstdint>
#include <cstddef>

// x [8,4096,512] fp32, W_enc [512,512], b_enc [512], code_book [128,512].
// Outputs: q, q, z -> 3 x B*DIM fp32. B = 32768.
//
// Round-N design: K-outer fused kernel. zacc[4][8] holds the full 512-col
// z row-block in registers; X is read ONCE (direct per-lane A-fragment
// global loads, no LDS staging); W/cb tiles are staged via double-buffered
// global_load_lds with stage(next) issued BEFORE compute(cur) so staging
// latency hides under the MFMA phase (2-phase pipeline). z written to HBM
// once, never re-read; S = z@cb^T via LDS hi/lo round-trip per 128-chunk.

#define DIM     512
#define NCODES  128

typedef _Float16 half8  __attribute__((ext_vector_type(8)));
typedef _Float16 half4h __attribute__((ext_vector_type(4)));
typedef float    f32x4  __attribute__((ext_vector_type(4)));

__device__ __forceinline__ void load_lds16(const void* gptr, void* ldsptr) {
    __builtin_amdgcn_global_load_lds(
        (const __attribute__((address_space(1))) uint32_t*)(uintptr_t)gptr,
        (__attribute__((address_space(3))) uint32_t*)(uintptr_t)ldsptr,
        16, 0, 0);
}

__device__ __forceinline__ void split_f32(float v, _Float16& h, _Float16& l) {
    h = (_Float16)v;
    l = (_Float16)(v - (float)h);
}

// ---------------------------------------------------------------------------
// Kernel P: split W (512x512) and cb (128x512) into f16 hi/lo arrays in ws.
// ---------------------------------------------------------------------------
__global__ __launch_bounds__(256) void presplit_kernel(
        const float* __restrict__ W, const float* __restrict__ cb,
        _Float16* __restrict__ Wh, _Float16* __restrict__ Wl,
        _Float16* __restrict__ Ch, _Float16* __restrict__ Cl) {
    const int gid = blockIdx.x * 256 + threadIdx.x;
    const float* src; _Float16 *dh, *dl; size_t e;
    if (gid < 65536) { src = W;  dh = Wh; dl = Wl; e = (size_t)gid * 4; }
    else             { src = cb; dh = Ch; dl = Cl; e = (size_t)(gid - 65536) * 4; }
    float4 v = *(const float4*)&src[e];
    _Float16 h0, h1, h2, h3, l0, l1, l2, l3;
    split_f32(v.x, h0, l0); split_f32(v.y, h1, l1);
    split_f32(v.z, h2, l2); split_f32(v.w, h3, l3);
    *(half4h*)&dh[e] = half4h{h0, h1, h2, h3};
    *(half4h*)&dl[e] = half4h{l0, l1, l2, l3};
}

// ---------------------------------------------------------------------------
// Kernel 0: per-code squared norms (fp32). 16 blocks x 256 thr.
// ---------------------------------------------------------------------------
__global__ void code_norms_kernel(const float* __restrict__ cb,
                                  float* __restrict__ cn) {
    const int tid = threadIdx.x;
    const int g = tid >> 5, l = tid & 31;
    const int code = blockIdx.x * 8 + g;
    const float4* row = (const float4*)(cb + (size_t)code * DIM);
    float s = 0.f;
    #pragma unroll
    for (int i = 0; i < 4; ++i) {
        float4 v = row[l + 32 * i];
        s = fmaf(v.x, v.x, s); s = fmaf(v.y, v.y, s);
        s = fmaf(v.z, v.z, s); s = fmaf(v.w, v.w, s);
    }
    #pragma unroll
    for (int m = 16; m >= 1; m >>= 1) s += __shfl_xor(s, m, 64);
    if (l == 0) cn[code] = s;
}

// ---------------------------------------------------------------------------
// Fused kernel: 512 blocks x 64 rows, 256 thr (4 waves), wave owns 16 rows.
// K-outer: for each k0 (16 steps of 32), 4 nc sub-steps accumulate
// zacc[nc] += X_k @ W_chunk^T (3-product f16 split). W tile (128x32 h+l)
// double-buffered in LDS; stage(next) issued before compute(cur); one
// __syncthreads per sub-step. X A-fragments are direct global loads
// (lane l: row rw+(l&15), k = k0 + (l>>4)*8), prefetched one k0 ahead.
// Tail: per nc chunk, epilogue (+bias, Z store, split->zhS/zlS) then
// S += z_chunk @ cb_chunk^T with the same pipelined cb staging.
// LDS swizzle (round-3 proven): BhS/BlS chunk p of row r holds global
// chunk p^((r>>1)&3).
// ---------------------------------------------------------------------------
__global__ __launch_bounds__(256, 2) void fused_kernel(
        const float* __restrict__ X, const _Float16* __restrict__ Wh,
        const _Float16* __restrict__ Wl, const _Float16* __restrict__ Ch,
        const _Float16* __restrict__ Cl, const float* __restrict__ cb,
        const float* __restrict__ bias, const float* __restrict__ cn,
        float* __restrict__ Z, float* __restrict__ q1,
        float* __restrict__ q2) {
    __shared__ _Float16 BhS[2][128][32];  // 16 KB (dbuf W tile, reused for cb)
    __shared__ _Float16 BlS[2][128][32];  // 16 KB
    __shared__ _Float16 zhS[64][132];     // 16.5 KB (stride 132: conflict-free)
    __shared__ _Float16 zlS[64][132];     // 16.5 KB
    __shared__ float    biasS[DIM];       // 2 KB
    __shared__ float    cnS[NCODES];
    __shared__ int      amin[64];

    const int tid  = threadIdx.x;
    const int lane = tid & 63;
    const int w    = tid >> 6;
    const int quad = lane >> 4;
    const int l15  = lane & 15;
    const int rw   = w * 16;              // wave's row base (local)
    const size_t row0 = (size_t)blockIdx.x * 64;
    const int wbase = tid & 192;          // wave-uniform thread base

    biasS[tid] = bias[tid];
    biasS[tid + 256] = bias[tid + 256];
    if (tid < NCODES) cnS[tid] = cn[tid];

    // Stage one 128x32-half tile (h and l) into LDS buffer with swizzle.
    // srcH/srcL already offset to (rowOff*DIM + kOff).
    auto stage_tile = [&](const _Float16* __restrict__ srcH,
                          const _Float16* __restrict__ srcL,
                          int buf) {
        #pragma unroll
        for (int i = 0; i < 2; ++i) {
            const int slot = i * 256 + tid;
            const int r = slot >> 2, p = slot & 3;
            const int g = p ^ ((r >> 1) & 3);
            load_lds16(&srcH[(size_t)r * DIM + g * 8],
                       (char*)&BhS[buf][0][0] + (size_t)(i * 256 + wbase) * 16);
            load_lds16(&srcL[(size_t)r * DIM + g * 8],
                       (char*)&BlS[buf][0][0] + (size_t)(i * 256 + wbase) * 16);
        }
    };

    // A-operand: lane l reads X row rw+(l&15), 8 consecutive k at (l>>4)*8.
    const float* xptr = X + (row0 + rw + l15) * DIM + quad * 8;

    f32x4 zacc[4][8] = {};

    // Prologue: stage (k0=0, nc=0) into buf0; prefetch first A fragment.
    stage_tile(Wh, Wl, 0);
    f32x4 a0 = *(const f32x4*)(xptr + 0);
    f32x4 a1 = *(const f32x4*)(xptr + 4);
    __syncthreads();

    for (int k0i = 0; k0i < 16; ++k0i) {
        const int k0 = k0i * 32;
        // Split current A fragment once per k0 (reused across 4 nc steps).
        _Float16 h[8], l[8];
        split_f32(a0[0], h[0], l[0]); split_f32(a0[1], h[1], l[1]);
        split_f32(a0[2], h[2], l[2]); split_f32(a0[3], h[3], l[3]);
        split_f32(a1[0], h[4], l[4]); split_f32(a1[1], h[5], l[5]);
        split_f32(a1[2], h[6], l[6]); split_f32(a1[3], h[7], l[7]);
        const half8 ah = half8{h[0], h[1], h[2], h[3], h[4], h[5], h[6], h[7]};
        const half8 al = half8{l[0], l[1], l[2], l[3], l[4], l[5], l[6], l[7]};
        // Prefetch next k0's A fragment.
        if (k0i < 15) {
            a0 = *(const f32x4*)(xptr + k0 + 32);
            a1 = *(const f32x4*)(xptr + k0 + 36);
        }

        #pragma unroll
        for (int nc = 0; nc < 4; ++nc) {
            const int cur = nc & 1;
            const int nxt = cur ^ 1;
            // Stage NEXT tile before computing current one (2-phase pipe).
            if (k0i < 15 || nc < 3) {
                const int ncn = (nc + 1) & 3;
                const int k0n = (nc == 3) ? (k0 + 32) : k0;
                stage_tile(Wh + (size_t)(ncn * 128) * DIM + k0n,
                           Wl + (size_t)(ncn * 128) * DIM + k0n, nxt);
            } else {
                // Last K sub-step: prefetch first cb tile (nc=0, ks=0).
                stage_tile(Ch, Cl, nxt);
            }
            // Compute from current buffer.
            #pragma unroll
            for (int j = 0; j < 8; ++j) {
                const int wrow = j * 16 + l15;
                const int p = quad ^ ((wrow >> 1) & 3);
                half8 bh = *(const half8*)&BhS[cur][wrow][p * 8];
                half8 bl = *(const half8*)&BlS[cur][wrow][p * 8];
                zacc[nc][j] = __builtin_amdgcn_mfma_f32_16x16x32_f16(ah, bh, zacc[nc][j], 0, 0, 0);
                zacc[nc][j] = __builtin_amdgcn_mfma_f32_16x16x32_f16(ah, bl, zacc[nc][j], 0, 0, 0);
                zacc[nc][j] = __builtin_amdgcn_mfma_f32_16x16x32_f16(al, bh, zacc[nc][j], 0, 0, 0);
            }
            __syncthreads();
        }
    }

    // Tail: per nc chunk, epilogue + S accumulation (pipelined cb staging).
    f32x4 Sacc[8] = {};
    #pragma unroll
    for (int nc = 0; nc < 4; ++nc) {
        const int col0 = nc * 128;
        // Epilogue: +bias, store z to global, split into zhS/zlS (A-layout).
        // D layout: row = rw + quad*4 + reg, col (within chunk) = j*16 + l15.
        #pragma unroll
        for (int j = 0; j < 8; ++j) {
            const int ccol = j * 16 + l15;
            const float bv = biasS[col0 + ccol];
            #pragma unroll
            for (int reg = 0; reg < 4; ++reg) {
                const int zrow = rw + quad * 4 + reg;
                const float v = zacc[nc][j][reg] + bv;
                Z[(row0 + zrow) * DIM + col0 + ccol] = v;
                _Float16 hh, ll; split_f32(v, hh, ll);
                zhS[zrow][ccol] = hh;
                zlS[zrow][ccol] = ll;
            }
        }
        __syncthreads();   // zhS/zlS ready (cb tile for ks=0 staged earlier)

        #pragma unroll
        for (int ks = 0; ks < 4; ++ks) {
            const int cur = ks & 1;
            const int nxt = cur ^ 1;
            if (!(nc == 3 && ks == 3)) {
                const int ncn = (ks == 3) ? nc + 1 : nc;
                const int ksn = (ks + 1) & 3;
                stage_tile(Ch + ncn * 128 + ksn * 32,
                           Cl + ncn * 128 + ksn * 32, nxt);
            }
            const half8 zh = *(const half8*)&zhS[rw + l15][ks * 32 + quad * 8];
            const half8 zl = *(const half8*)&zlS[rw + l15][ks * 32 + quad * 8];
            #pragma unroll
            for (int j = 0; j < 8; ++j) {
                const int crow = j * 16 + l15;
                const int p = quad ^ ((crow >> 1) & 3);
                half8 ch = *(const half8*)&BhS[cur][crow][p * 8];
                half8 cl = *(const half8*)&BlS[cur][crow][p * 8];
                Sacc[j] = __builtin_amdgcn_mfma_f32_16x16x32_f16(zh, ch, Sacc[j], 0, 0, 0);
                Sacc[j] = __builtin_amdgcn_mfma_f32_16x16x32_f16(zh, cl, Sacc[j], 0, 0, 0);
                Sacc[j] = __builtin_amdgcn_mfma_f32_16x16x32_f16(zl, ch, Sacc[j], 0, 0, 0);
            }
            __syncthreads();
        }
    }

    // Row argmin: lane holds S row rw+quad*4+reg, code j*16+l15.
    #pragma unroll
    for (int reg = 0; reg < 4; ++reg) {
        float bv = fmaf(-2.f, Sacc[0][reg], cnS[l15]);
        int bi = l15;
        #pragma unroll
        for (int j = 1; j < 8; ++j) {
            const int c = j * 16 + l15;
            const float s = fmaf(-2.f, Sacc[j][reg], cnS[c]);
            if (s < bv) { bv = s; bi = c; }
        }
        #pragma unroll
        for (int m = 1; m <= 8; m <<= 1) {
            const float ov = __shfl_xor(bv, m, 64);
            const int   oi = __shfl_xor(bi, m, 64);
            if (ov < bv || (ov == bv && oi < bi)) { bv = ov; bi = oi; }
        }
        if (l15 == 0) amin[rw + quad * 4 + reg] = bi;
    }
    __syncthreads();

    // Gather: wave per row, 8 floats/lane, bitwise codebook copy to q1,q2.
    for (int r = w; r < 64; r += 4) {
        const int idx = amin[r];
        const float4* src = (const float4*)&cb[(size_t)idx * DIM];
        float4 v0 = src[lane * 2 + 0];
        float4 v1 = src[lane * 2 + 1];
        float4* d1 = (float4*)&q1[(row0 + r) * DIM];
        float4* d2 = (float4*)&q2[(row0 + r) * DIM];
        d1[lane * 2 + 0] = v0; d1[lane * 2 + 1] = v1;
        d2[lane * 2 + 0] = v0; d2[lane * 2 + 1] = v1;
    }
}

// ---------------------------------------------------------------------------
extern "C" void kernel_launch(void* const* d_in, const int* in_sizes, int n_in,
                              void* d_out, int out_size, void* d_ws, size_t ws_size,
                              hipStream_t stream) {
    const float* x    = (const float*)d_in[0];
    const float* Wenc = (const float*)d_in[1];
    const float* benc = (const float*)d_in[2];
    const float* cb   = (const float*)d_in[3];

    const int B = in_sizes[0] / DIM;             // 32768

    float* out = (float*)d_out;
    float* q1 = out;
    float* q2 = out + (size_t)B * DIM;
    float* z  = out + (size_t)2 * B * DIM;

    // ws carve (16B-aligned): cn | Wh | Wl | Ch | Cl  (~1.3 MB total)
    char* wsb = (char*)d_ws;
    float*    cn = (float*)wsb;                          // 512 B
    _Float16* Wh = (_Float16*)(wsb + 4096);              // 512 KB
    _Float16* Wl = (_Float16*)(wsb + 4096 + 524288);     // 512 KB
    _Float16* Ch = (_Float16*)(wsb + 4096 + 1048576);    // 128 KB
    _Float16* Cl = (_Float16*)(wsb + 4096 + 1179648);    // 128 KB

    presplit_kernel<<<320, 256, 0, stream>>>(Wenc, cb, Wh, Wl, Ch, Cl);
    code_norms_kernel<<<NCODES / 8, 256, 0, stream>>>(cb, cn);

    fused_kernel<<<B / 64, 256, 0, stream>>>(x, Wh, Wl, Ch, Cl, cb, benc, cn,
                                             z, q1, q2);
}